// Round 1
// baseline (111.510 us; speedup 1.0000x reference)
//
#include <hip/hip_runtime.h>

// out[b,c,h,w] = (c % 2 == 0) ? relu(x) : x
// x: (16, 64, 256, 256) float32, contiguous.
// Elementwise, memory-bound. float4 vectorized, grid-stride loop.
//
// Channel of element e = (e >> 16) & 63  (256*256 = 65536 = 2^16).
// For float4 index i (e = 4*i), channel = (i >> 14) & 63; mask = even channel
// => ((i >> 14) & 1) == 0. Mask is a pure function of index (posIdx in the
// reference is arange(64) % 2 == 0), so no need to load the bool array.

__global__ __launch_bounds__(256) void Grid2DPartialPositiver_kernel(
    const float4* __restrict__ in, float4* __restrict__ out, unsigned int n4) {
    unsigned int i = blockIdx.x * blockDim.x + threadIdx.x;
    const unsigned int stride = gridDim.x * blockDim.x;
    for (; i < n4; i += stride) {
        float4 v = in[i];
        const bool pos = ((i >> 14) & 1u) == 0u;  // even channel -> relu
        if (pos) {
            v.x = fmaxf(v.x, 0.0f);
            v.y = fmaxf(v.y, 0.0f);
            v.z = fmaxf(v.z, 0.0f);
            v.w = fmaxf(v.w, 0.0f);
        }
        out[i] = v;
    }
}

extern "C" void kernel_launch(void* const* d_in, const int* in_sizes, int n_in,
                              void* d_out, int out_size, void* d_ws, size_t ws_size,
                              hipStream_t stream) {
    const float4* x = (const float4*)d_in[0];
    float4* out = (float4*)d_out;
    // total elements = 16*64*256*256 = 67,108,864 ; float4 count = 16,777,216
    const unsigned int n4 = (unsigned int)(out_size / 4);
    const int block = 256;
    const int grid = 2048;  // 8 blocks/CU * 256 CUs; grid-stride covers rest
    Grid2DPartialPositiver_kernel<<<grid, block, 0, stream>>>(x, out, n4);
}

// Round 2
// 97.675 us; speedup vs baseline: 1.1417x; 1.1417x over previous
//
#include <hip/hip_runtime.h>

// out[b,c,h,w] = (c % 2 == 0) ? relu(x) : x ; x: (16,64,256,256) f32 contiguous.
// Memory-bound streaming op. float4 (16B/lane), unroll-4 blocked so each
// thread has 4 independent loads in flight; nontemporal load/store (read-once/
// write-once data, skip cache allocate).
//
// Channel of element e = (e >> 16) & 63; for float4 index i, even-channel
// mask = ((i >> 14) & 1) == 0 (pure function of index; posIdx is arange%2==0).

typedef float f32x4 __attribute__((ext_vector_type(4)));

__device__ __forceinline__ f32x4 relu4_if(f32x4 v, bool pos) {
    if (pos) {
        v.x = fmaxf(v.x, 0.0f);
        v.y = fmaxf(v.y, 0.0f);
        v.z = fmaxf(v.z, 0.0f);
        v.w = fmaxf(v.w, 0.0f);
    }
    return v;
}

__global__ __launch_bounds__(256) void Grid2DPartialPositiver_kernel(
    const f32x4* __restrict__ in, f32x4* __restrict__ out, unsigned int n4) {
    const unsigned int t = blockIdx.x * 256u + threadIdx.x;
    const unsigned int T = gridDim.x * 256u;
    const unsigned int i0 = t;
    const unsigned int i1 = t + T;
    const unsigned int i2 = t + 2u * T;
    const unsigned int i3 = t + 3u * T;

    if (i3 < n4) {
        // fast path: 4 independent loads issued back-to-back, then stores
        f32x4 v0 = __builtin_nontemporal_load(&in[i0]);
        f32x4 v1 = __builtin_nontemporal_load(&in[i1]);
        f32x4 v2 = __builtin_nontemporal_load(&in[i2]);
        f32x4 v3 = __builtin_nontemporal_load(&in[i3]);
        v0 = relu4_if(v0, ((i0 >> 14) & 1u) == 0u);
        v1 = relu4_if(v1, ((i1 >> 14) & 1u) == 0u);
        v2 = relu4_if(v2, ((i2 >> 14) & 1u) == 0u);
        v3 = relu4_if(v3, ((i3 >> 14) & 1u) == 0u);
        __builtin_nontemporal_store(v0, &out[i0]);
        __builtin_nontemporal_store(v1, &out[i1]);
        __builtin_nontemporal_store(v2, &out[i2]);
        __builtin_nontemporal_store(v3, &out[i3]);
    } else {
        // tail (only if n4 not divisible by 4*T)
        for (unsigned int i = i0; i < n4; i += T) {
            f32x4 v = __builtin_nontemporal_load(&in[i]);
            v = relu4_if(v, ((i >> 14) & 1u) == 0u);
            __builtin_nontemporal_store(v, &out[i]);
        }
    }
}

extern "C" void kernel_launch(void* const* d_in, const int* in_sizes, int n_in,
                              void* d_out, int out_size, void* d_ws, size_t ws_size,
                              hipStream_t stream) {
    const f32x4* x = (const f32x4*)d_in[0];
    f32x4* out = (f32x4*)d_out;
    const unsigned int n4 = (unsigned int)(out_size / 4);  // 16,777,216
    const int block = 256;
    // exact single sweep: grid*block*4 == n4  (16384 blocks for this shape)
    const int grid = (int)((n4 + (unsigned)(block * 4) - 1) / (unsigned)(block * 4));
    Grid2DPartialPositiver_kernel<<<grid, block, 0, stream>>>(x, out, n4);
}